// Round 9
// baseline (88.621 us; speedup 1.0000x reference)
//
#include <hip/hip_runtime.h>

#define HH 128
#define WW 128
#define HWSZ (HH*WW)
#define NB 4
#define KK 9
#define XSTR 96   // NHWC channel stride in bf16 elems (192 B): c0-63 input, c64 mask, c65-95 zero

typedef short bf16x8 __attribute__((ext_vector_type(8)));
typedef float f32x4 __attribute__((ext_vector_type(4)));

union U4 { uint4 v; unsigned a[4]; };

__device__ __forceinline__ short f2bf(float f) {
    union { float f; unsigned u; } v; v.f = f;
    unsigned r = v.u + 0x7FFFu + ((v.u >> 16) & 1u);
    return (short)(r >> 16);
}
__device__ __forceinline__ float bflo(unsigned dw) {
    union { unsigned u; float f; } v; v.u = dw << 16; return v.f;
}
__device__ __forceinline__ float bfhi(unsigned dw) {
    union { unsigned u; float f; } v; v.u = dw & 0xFFFF0000u; return v.f;
}
__device__ __forceinline__ unsigned cvtpk(float lo, float hi) {
    unsigned r;
    asm("v_cvt_pk_bf16_f32 %0, %1, %2" : "=v"(r) : "v"(lo), "v"(hi));
    return r;
}

// ---------------- prep: NHWC-bf16 transpose (banded) + weight repack ----------------
// xt : [NB*HWSZ][96] bf16: c0-63 input, c64 = mask_in, c65-95 = 0
// wd2: deform B frags [ks(2)][tap(9)][nt(4)][lane(64)][8] bf16 (36,864)
// wc2: conv   B frags [ks(3)][tap(9)][nt(2)][lane(64)][8] bf16 (27,648); ks=2 = mask channel
__global__ __launch_bounds__(256) void prep_kernel(
    const float* __restrict__ input,
    const float* __restrict__ mask_in,
    const float* __restrict__ weight,
    const float* __restrict__ offset_w,
    const float* __restrict__ mask_w,
    short* __restrict__ xt,
    short* __restrict__ wd2,
    short* __restrict__ wc2)
{
    __shared__ short lds[64 * 104];
    int bid = blockIdx.x;
    if (bid < 1024) {
        int wg = ((bid & 7) << 7) | (bid >> 3);   // XCD band swizzle
        int g0 = wg * 64;
        int b  = g0 >> 14;
        int p0 = g0 & (HWSZ - 1);
        int px = threadIdx.x & 63;
        int cq = threadIdx.x >> 6;
#pragma unroll
        for (int it = 0; it < 24; ++it) {
            int c = it * 4 + cq;
            float v;
            if (c < 64)       v = input[((size_t)(b * 64 + c)) * HWSZ + p0 + px];
            else if (c == 64) v = mask_in[(size_t)b * HWSZ + p0 + px];
            else              v = 0.f;
            lds[px * 104 + c] = f2bf(v);
        }
        __syncthreads();
#pragma unroll
        for (int it = 0; it < 3; ++it) {
            int idx = it * 256 + threadIdx.x;
            if (idx < 768) {
                int ppx = idx / 12, s = idx - ppx * 12;
                bf16x8 v = *(const bf16x8*)&lds[ppx * 104 + s * 8];
                *(bf16x8*)&xt[((size_t)(g0 + ppx)) * XSTR + s * 8] = v;
            }
        }
    } else {
        int idx = (bid - 1024) * 256 + threadIdx.x;   // 0..36863
        if (idx < 36864) {
            int j = idx & 7, l = (idx >> 3) & 63, f = idx >> 9;
            int nt = f & 3, t9 = f >> 2;
            int k = t9 % 9, ks = t9 / 9;
            int o = nt * 16 + (l & 15);
            int c = ks * 32 + ((l >> 4) & 3) * 8 + j;
            wd2[idx] = f2bf(weight[(o * 64 + c) * 9 + k]);
        }
        if (idx < 27648) {
            int j = idx & 7, l = (idx >> 3) & 63, f = idx >> 9;
            int nt = f & 1, t9 = f >> 1;
            int k = t9 % 9, ks = t9 / 9;
            int o = nt * 16 + (l & 15);
            int c = ks * 32 + ((l >> 4) & 3) * 8 + j;
            float v = 0.f;
            if (c <= 64) {
                if (o < 18)      v = offset_w[(o * 65 + c) * 9 + k];
                else if (o < 27) v = mask_w[((o - 18) * 65 + c) * 9 + k];
            }
            wc2[idx] = f2bf(v);
        }
    }
}

// ---------------- conv (65ch in, 27ch out, 3x3, pad 1): MFMA, depth-1 pipelined A ----------------
// off_px: [NB*HWSZ][32] f32: 0..17 offsets (dy/dx), 18..26 sigmoid(mask)
__global__ __launch_bounds__(256, 4) void conv_offset_mfma(
    const short* __restrict__ xt, const bf16x8* __restrict__ wc,
    const float* __restrict__ offset_b, const float* __restrict__ mask_b,
    float* __restrict__ off_px)
{
    int bid = blockIdx.x;
    int wg = ((bid & 7) << 7) | (bid >> 3);
    int wid = threadIdx.x >> 6, lane = threadIdx.x & 63;
    int r = lane & 15, lg = lane >> 4;
    int g0 = wg * 64 + wid * 16;
    int gp = g0 + r;
    int b = gp >> 14, p = gp & (HWSZ - 1);
    int i = p >> 7, j = p & 127;
    const short* xb = xt + ((size_t)(b << 14)) * XSTR + lg * 8;

    f32x4 acc0 = {0,0,0,0}, acc1 = {0,0,0,0};
    U4 ab[2][3];
    bool vb[2];

#define CADDR(T, B) do {                                                      \
        int yy = i + (T) / 3 - 1, xx = j + (T) % 3 - 1;                       \
        bool v = ((unsigned)yy < HH) && ((unsigned)xx < WW);                  \
        int nb = (v ? yy * WW + xx : 0) * XSTR;                               \
        vb[B] = v;                                                            \
        ab[B][0].v = *(const uint4*)(xb + nb);                                \
        ab[B][1].v = *(const uint4*)(xb + nb + 32);                           \
        ab[B][2].v = *(const uint4*)(xb + nb + 64);                           \
    } while (0)

    CADDR(0, 0);
#pragma unroll
    for (int t = 0; t < 9; ++t) {
        int cb = t & 1, nbuf = cb ^ 1;
        if (t < 8) CADDR(t + 1, nbuf);
        __builtin_amdgcn_sched_barrier(0);
#pragma unroll
        for (int ks = 0; ks < 3; ++ks) {
            union { bf16x8 s8; uint4 u; } A;
            A.u = ab[cb][ks].v;
            if (!vb[cb]) { A.u.x = 0; A.u.y = 0; A.u.z = 0; A.u.w = 0; }
            const bf16x8* wck = wc + ((ks * 9 + t) * 2) * 64 + lane;
            bf16x8 B0 = wck[0];
            bf16x8 B1 = wck[64];
            acc0 = __builtin_amdgcn_mfma_f32_16x16x32_bf16(A.s8, B0, acc0, 0, 0, 0);
            acc1 = __builtin_amdgcn_mfma_f32_16x16x32_bf16(A.s8, B1, acc1, 0, 0, 0);
        }
    }
#undef CADDR

    int oc = lane & 15, pr0 = lg * 4;
#pragma unroll
    for (int rr = 0; rr < 4; ++rr) {
        int gpix = g0 + pr0 + rr;
        float* orow = off_px + (size_t)gpix * 32;
        orow[oc] = acc0[rr] + offset_b[oc];
        int oc2 = 16 + oc;
        if (oc2 < 18) {
            orow[oc2] = acc1[rr] + offset_b[oc2];
        } else if (oc2 < 27) {
            float z = acc1[rr] + mask_b[oc2 - 18];
            orow[oc2] = 1.f / (1.f + __expf(-z));
        }
    }
}

// ---------------- main deformable conv: depth-1 pipelined gathers + MFMA + fused update_mask ----------------
__global__ __launch_bounds__(256, 4) void deform_main_mfma(
    const short* __restrict__ xt, const float* __restrict__ off_px,
    const float* __restrict__ mask_in, const bf16x8* __restrict__ wd,
    const float* __restrict__ bias,
    float* __restrict__ out, float* __restrict__ upd)
{
    int bid = blockIdx.x;
    int wg = ((bid & 7) << 7) | (bid >> 3);
    int wid = threadIdx.x >> 6, lane = threadIdx.x & 63;
    int r = lane & 15, lg = lane >> 4;
    int g0 = wg * 64 + wid * 16;
    int gp = g0 + r;
    int b = gp >> 14, p = gp & (HWSZ - 1);
    int i = p >> 7, j = p & 127;
    const short* xb = xt + ((size_t)(b << 14)) * XSTR + lg * 8;
    const float* mb = mask_in + (size_t)b * HWSZ;

    float ov[28];
    {
        const float4* op = (const float4*)(off_px + (size_t)gp * 32);
#pragma unroll
        for (int q = 0; q < 7; ++q) {
            float4 t = op[q];
            ov[4*q+0] = t.x; ov[4*q+1] = t.y; ov[4*q+2] = t.z; ov[4*q+3] = t.w;
        }
    }

    f32x4 acc0 = {0,0,0,0}, acc1 = {0,0,0,0}, acc2 = {0,0,0,0}, acc3 = {0,0,0,0};
    float um = 0.f;

    // pipeline state: [buf][...], all statically indexed after full unroll
    U4    gb[2][8];        // corner c(0..3) * 2 + ks
    float wgt[2][4], rwv[2][4], mbv[2][4];

#define TAPADDR(K, B) do {                                                    \
        float dy = ov[2*(K)], dx = ov[2*(K)+1], m = ov[18+(K)];               \
        float py  = dy + (float)((K)/3 + i - 1);                              \
        float pxx = dx + (float)((K)%3 + j - 1);                              \
        float fy = floorf(py), fx = floorf(pxx);                              \
        float wy = py - fy, wx = pxx - fx;                                    \
        int y0 = (int)fy, x0 = (int)fx;                                       \
        int y1 = y0 + 1, x1 = x0 + 1;                                         \
        bool vy0 = (unsigned)y0 < HH, vy1 = (unsigned)y1 < HH;                \
        bool vx0 = (unsigned)x0 < WW, vx1 = (unsigned)x1 < WW;                \
        int yc0 = min(max(y0, 0), HH - 1), yc1 = min(max(y1, 0), HH - 1);     \
        int xc0 = min(max(x0, 0), WW - 1), xc1 = min(max(x1, 0), WW - 1);     \
        float r00 = (vy0 && vx0) ? (1.f - wy) * (1.f - wx) : 0.f;             \
        float r01 = (vy0 && vx1) ? (1.f - wy) * wx : 0.f;                     \
        float r10 = (vy1 && vx0) ? wy * (1.f - wx) : 0.f;                     \
        float r11 = (vy1 && vx1) ? wy * wx : 0.f;                             \
        int i00 = yc0 * WW + xc0, i01 = yc0 * WW + xc1;                       \
        int i10 = yc1 * WW + xc0, i11 = yc1 * WW + xc1;                       \
        rwv[B][0] = r00; rwv[B][1] = r01; rwv[B][2] = r10; rwv[B][3] = r11;   \
        wgt[B][0] = r00 * m; wgt[B][1] = r01 * m;                             \
        wgt[B][2] = r10 * m; wgt[B][3] = r11 * m;                             \
        gb[B][0].v = *(const uint4*)(xb + i00 * XSTR);                        \
        gb[B][1].v = *(const uint4*)(xb + i00 * XSTR + 32);                   \
        gb[B][2].v = *(const uint4*)(xb + i01 * XSTR);                        \
        gb[B][3].v = *(const uint4*)(xb + i01 * XSTR + 32);                   \
        gb[B][4].v = *(const uint4*)(xb + i10 * XSTR);                        \
        gb[B][5].v = *(const uint4*)(xb + i10 * XSTR + 32);                   \
        gb[B][6].v = *(const uint4*)(xb + i11 * XSTR);                        \
        gb[B][7].v = *(const uint4*)(xb + i11 * XSTR + 32);                   \
        mbv[B][0] = mb[i00]; mbv[B][1] = mb[i01];                             \
        mbv[B][2] = mb[i10]; mbv[B][3] = mb[i11];                             \
    } while (0)

    TAPADDR(0, 0);
#pragma unroll
    for (int k = 0; k < KK; ++k) {
        int cb = k & 1, nbuf = cb ^ 1;
        if (k < 8) TAPADDR(k + 1, nbuf);
        __builtin_amdgcn_sched_barrier(0);

        um += rwv[cb][0] * mbv[cb][0] + rwv[cb][1] * mbv[cb][1]
            + rwv[cb][2] * mbv[cb][2] + rwv[cb][3] * mbv[cb][3];

#pragma unroll
        for (int ks = 0; ks < 2; ++ks) {
            union { bf16x8 s8; unsigned u[4]; } A;
#pragma unroll
            for (int q = 0; q < 4; ++q) {
                unsigned d00 = gb[cb][0 * 2 + ks].a[q], d01 = gb[cb][1 * 2 + ks].a[q];
                unsigned d10 = gb[cb][2 * 2 + ks].a[q], d11 = gb[cb][3 * 2 + ks].a[q];
                float vlo = fmaf(wgt[cb][0], bflo(d00), fmaf(wgt[cb][1], bflo(d01),
                            fmaf(wgt[cb][2], bflo(d10), wgt[cb][3] * bflo(d11))));
                float vhi = fmaf(wgt[cb][0], bfhi(d00), fmaf(wgt[cb][1], bfhi(d01),
                            fmaf(wgt[cb][2], bfhi(d10), wgt[cb][3] * bfhi(d11))));
                A.u[q] = cvtpk(vlo, vhi);
            }
            const bf16x8* wbk = wd + ((ks * 9 + k) * 4) * 64 + lane;
            bf16x8 B0 = wbk[0];
            bf16x8 B1 = wbk[64];
            bf16x8 B2 = wbk[128];
            bf16x8 B3 = wbk[192];
            acc0 = __builtin_amdgcn_mfma_f32_16x16x32_bf16(A.s8, B0, acc0, 0, 0, 0);
            acc1 = __builtin_amdgcn_mfma_f32_16x16x32_bf16(A.s8, B1, acc1, 0, 0, 0);
            acc2 = __builtin_amdgcn_mfma_f32_16x16x32_bf16(A.s8, B2, acc2, 0, 0, 0);
            acc3 = __builtin_amdgcn_mfma_f32_16x16x32_bf16(A.s8, B3, acc3, 0, 0, 0);
        }
    }
#undef TAPADDR

    um = fminf(fmaxf(64.f * um, 0.f), 1.f);
    if (lane < 16) upd[g0 + lane] = um;

    int oc = lane & 15;
    int pr0 = lg * 4;
    float u[4];
#pragma unroll
    for (int rr = 0; rr < 4; ++rr) u[rr] = __shfl(um, pr0 + rr, 64);

#define STORE_NT(ACC, NT)                                                     \
    {                                                                         \
        float bo = bias[(NT) * 16 + oc];                                      \
        _Pragma("unroll")                                                     \
        for (int rr = 0; rr < 4; ++rr) {                                      \
            int gg = g0 + pr0 + rr;                                           \
            int bb = gg >> 14;                                                \
            int pp = gg & (HWSZ - 1);                                         \
            out[((size_t)(bb * 64 + (NT) * 16 + oc)) * HWSZ + pp] =           \
                (ACC[rr] + bo) * u[rr];                                       \
        }                                                                     \
    }
    STORE_NT(acc0, 0)
    STORE_NT(acc1, 1)
    STORE_NT(acc2, 2)
    STORE_NT(acc3, 3)
#undef STORE_NT
}

extern "C" void kernel_launch(void* const* d_in, const int* in_sizes, int n_in,
                              void* d_out, int out_size, void* d_ws, size_t ws_size,
                              hipStream_t stream) {
    const float* input    = (const float*)d_in[0];
    const float* mask_in  = (const float*)d_in[1];
    const float* weight   = (const float*)d_in[2];
    const float* bias     = (const float*)d_in[3];
    const float* offset_w = (const float*)d_in[4];
    const float* offset_b = (const float*)d_in[5];
    const float* mask_w   = (const float*)d_in[6];
    const float* mask_b   = (const float*)d_in[7];

    float* out = (float*)d_out;
    float* upd = out + (size_t)NB * 64 * HWSZ;

    float* ws     = (float*)d_ws;
    float* off_px = ws;                                   // 65536*32 f32 = 8.4 MB
    short* wd2    = (short*)(off_px + (size_t)65536*32);  // 36,864 bf16
    short* wc2    = wd2 + 36864;                          // 27,648 bf16
    short* xt     = wc2 + 27648;                          // 65536*96 bf16 = 12.6 MB

    hipLaunchKernelGGL(prep_kernel, dim3(1168), dim3(256), 0, stream,
                       input, mask_in, weight, offset_w, mask_w, xt, wd2, wc2);
    hipLaunchKernelGGL(conv_offset_mfma, dim3(1024), dim3(256), 0, stream,
                       xt, (const bf16x8*)wc2, offset_b, mask_b, off_px);
    hipLaunchKernelGGL(deform_main_mfma, dim3(1024), dim3(256), 0, stream,
                       xt, off_px, mask_in, (const bf16x8*)wd2, bias, out, upd);
}

// Round 10
// 68.453 us; speedup vs baseline: 1.2946x; 1.2946x over previous
//
#include <hip/hip_runtime.h>

#define HH 128
#define WW 128
#define HWSZ (HH*WW)
#define NB 4
#define KK 9
#define PS (HWSZ*8)          // plane stride in shorts: 16384 px * 8 ch
#define IMS (12*PS)          // image stride in shorts: 12 channel-blocks

typedef short bf16x8 __attribute__((ext_vector_type(8)));
typedef float f32x4 __attribute__((ext_vector_type(4)));

union U4 { uint4 v; unsigned a[4]; };

__device__ __forceinline__ short f2bf(float f) {
    union { float f; unsigned u; } v; v.f = f;
    unsigned r = v.u + 0x7FFFu + ((v.u >> 16) & 1u);
    return (short)(r >> 16);
}
__device__ __forceinline__ float bflo(unsigned dw) {
    union { unsigned u; float f; } v; v.u = dw << 16; return v.f;
}
__device__ __forceinline__ float bfhi(unsigned dw) {
    union { unsigned u; float f; } v; v.u = dw & 0xFFFF0000u; return v.f;
}
__device__ __forceinline__ unsigned cvtpk(float lo, float hi) {
    unsigned r;
    asm("v_cvt_pk_bf16_f32 %0, %1, %2" : "=v"(r) : "v"(lo), "v"(hi));
    return r;
}

// ---------------- prep: channel-block-planar bf16 transpose + weight repack ----------------
// xt2: [b][cb(12)][pixel(16384)][8ch] bf16. cb0-7 = input ch 0..63, cb8 = {mask,0...}, cb9-11 = 0
// wd2: deform B frags [ks(2)][tap(9)][nt(4)][lane(64)][8] bf16 (36,864)
// wc2: conv   B frags [ks(3)][tap(9)][nt(2)][lane(64)][8] bf16 (27,648); ks=2 = mask channel
__global__ __launch_bounds__(256) void prep_kernel(
    const float* __restrict__ input,
    const float* __restrict__ mask_in,
    const float* __restrict__ weight,
    const float* __restrict__ offset_w,
    const float* __restrict__ mask_w,
    short* __restrict__ xt2,
    short* __restrict__ wd2,
    short* __restrict__ wc2)
{
    __shared__ short lds[64 * 104];
    int bid = blockIdx.x;
    if (bid < 1024) {
        int wg = ((bid & 7) << 7) | (bid >> 3);   // XCD band swizzle
        int g0 = wg * 64;
        int b  = g0 >> 14;
        int p0 = g0 & (HWSZ - 1);
        int px = threadIdx.x & 63;
        int cq = threadIdx.x >> 6;
#pragma unroll
        for (int it = 0; it < 24; ++it) {
            int c = it * 4 + cq;
            float v;
            if (c < 64)       v = input[((size_t)(b * 64 + c)) * HWSZ + p0 + px];
            else if (c == 64) v = mask_in[(size_t)b * HWSZ + p0 + px];
            else              v = 0.f;
            lds[px * 104 + c] = f2bf(v);
        }
        __syncthreads();
#pragma unroll
        for (int it = 0; it < 3; ++it) {
            int idx = it * 256 + threadIdx.x;
            if (idx < 768) {
                int ppx = idx / 12, cb = idx - ppx * 12;
                bf16x8 v = *(const bf16x8*)&lds[ppx * 104 + cb * 8];
                *(bf16x8*)&xt2[(size_t)b * IMS + (size_t)cb * PS + (size_t)(p0 + ppx) * 8] = v;
            }
        }
    } else {
        int idx = (bid - 1024) * 256 + threadIdx.x;   // 0..36863
        if (idx < 36864) {
            int j = idx & 7, l = (idx >> 3) & 63, f = idx >> 9;
            int nt = f & 3, t9 = f >> 2;
            int k = t9 % 9, ks = t9 / 9;
            int o = nt * 16 + (l & 15);
            int c = ks * 32 + ((l >> 4) & 3) * 8 + j;
            wd2[idx] = f2bf(weight[(o * 64 + c) * 9 + k]);
        }
        if (idx < 27648) {
            int j = idx & 7, l = (idx >> 3) & 63, f = idx >> 9;
            int nt = f & 1, t9 = f >> 1;
            int k = t9 % 9, ks = t9 / 9;
            int o = nt * 16 + (l & 15);
            int c = ks * 32 + ((l >> 4) & 3) * 8 + j;
            float v = 0.f;
            if (c <= 64) {
                if (o < 18)      v = offset_w[(o * 65 + c) * 9 + k];
                else if (o < 27) v = mask_w[((o - 18) * 65 + c) * 9 + k];
            }
            wc2[idx] = f2bf(v);
        }
    }
}

// ---------------- conv (65ch in, 27ch out, 3x3, pad 1): MFMA, planar coalesced A ----------------
// off_px: [NB*HWSZ][32] f32: 0..17 offsets (dy/dx), 18..26 sigmoid(mask)
__global__ __launch_bounds__(256, 4) void conv_offset_mfma(
    const short* __restrict__ xt2, const bf16x8* __restrict__ wc,
    const float* __restrict__ offset_b, const float* __restrict__ mask_b,
    float* __restrict__ off_px)
{
    int bid = blockIdx.x;
    int wg = ((bid & 7) << 7) | (bid >> 3);
    int wid = threadIdx.x >> 6, lane = threadIdx.x & 63;
    int r = lane & 15, lg = lane >> 4;
    int g0 = wg * 64 + wid * 16;
    int gp = g0 + r;
    int b = gp >> 14, p = gp & (HWSZ - 1);
    int i = p >> 7, j = p & 127;
    const short* xq = xt2 + (size_t)b * IMS + (size_t)lg * PS;   // plane cb = ks*4+lg

    f32x4 acc0 = {0,0,0,0}, acc1 = {0,0,0,0};

#pragma unroll
    for (int t = 0; t < 9; ++t) {
        int yy = i + t / 3 - 1, xx = j + t % 3 - 1;
        bool v = ((unsigned)yy < HH) && ((unsigned)xx < WW);
        int nb = (v ? yy * WW + xx : 0) * 8;
        union { bf16x8 s8; uint4 u; } A[3];
#pragma unroll
        for (int ks = 0; ks < 3; ++ks) {
            A[ks].u = *(const uint4*)(xq + (size_t)ks * 4 * PS + nb);
            if (!v) { A[ks].u.x = 0; A[ks].u.y = 0; A[ks].u.z = 0; A[ks].u.w = 0; }
        }
#pragma unroll
        for (int ks = 0; ks < 3; ++ks) {
            const bf16x8* wck = wc + ((ks * 9 + t) * 2) * 64 + lane;
            bf16x8 B0 = wck[0];
            bf16x8 B1 = wck[64];
            acc0 = __builtin_amdgcn_mfma_f32_16x16x32_bf16(A[ks].s8, B0, acc0, 0, 0, 0);
            acc1 = __builtin_amdgcn_mfma_f32_16x16x32_bf16(A[ks].s8, B1, acc1, 0, 0, 0);
        }
    }

    int oc = lane & 15, pr0 = lg * 4;
#pragma unroll
    for (int rr = 0; rr < 4; ++rr) {
        int gpix = g0 + pr0 + rr;
        float* orow = off_px + (size_t)gpix * 32;
        orow[oc] = acc0[rr] + offset_b[oc];
        int oc2 = 16 + oc;
        if (oc2 < 18) {
            orow[oc2] = acc1[rr] + offset_b[oc2];
        } else if (oc2 < 27) {
            float z = acc1[rr] + mask_b[oc2 - 18];
            orow[oc2] = 1.f / (1.f + __expf(-z));
        }
    }
}

// ---------------- main deformable conv: MFMA, planar coalesced gathers, fused update_mask ----------------
__global__ __launch_bounds__(256, 4) void deform_main_mfma(
    const short* __restrict__ xt2, const float* __restrict__ off_px,
    const float* __restrict__ mask_in, const bf16x8* __restrict__ wd,
    const float* __restrict__ bias,
    float* __restrict__ out, float* __restrict__ upd)
{
    int bid = blockIdx.x;
    int wg = ((bid & 7) << 7) | (bid >> 3);
    int wid = threadIdx.x >> 6, lane = threadIdx.x & 63;
    int r = lane & 15, lg = lane >> 4;
    int g0 = wg * 64 + wid * 16;
    int gp = g0 + r;
    int b = gp >> 14, p = gp & (HWSZ - 1);
    int i = p >> 7, j = p & 127;
    const short* xq = xt2 + (size_t)b * IMS + (size_t)lg * PS;   // plane cb = ks*4+lg
    const float* mb = mask_in + (size_t)b * HWSZ;

    float ov[28];
    {
        const float4* op = (const float4*)(off_px + (size_t)gp * 32);
#pragma unroll
        for (int q = 0; q < 7; ++q) {
            float4 t = op[q];
            ov[4*q+0] = t.x; ov[4*q+1] = t.y; ov[4*q+2] = t.z; ov[4*q+3] = t.w;
        }
    }

    f32x4 acc0 = {0,0,0,0}, acc1 = {0,0,0,0}, acc2 = {0,0,0,0}, acc3 = {0,0,0,0};
    float um = 0.f;

#pragma unroll
    for (int k = 0; k < KK; ++k) {
        float dy = ov[2*k], dx = ov[2*k+1], m = ov[18+k];
        float py  = dy + (float)(k / 3 + i - 1);
        float pxx = dx + (float)(k % 3 + j - 1);
        float fy = floorf(py), fx = floorf(pxx);
        float wy = py - fy, wx = pxx - fx;
        int y0 = (int)fy, x0 = (int)fx;
        int y1 = y0 + 1, x1 = x0 + 1;
        bool vy0 = (unsigned)y0 < HH, vy1 = (unsigned)y1 < HH;
        bool vx0 = (unsigned)x0 < WW, vx1 = (unsigned)x1 < WW;
        int yc0 = min(max(y0, 0), HH - 1), yc1 = min(max(y1, 0), HH - 1);
        int xc0 = min(max(x0, 0), WW - 1), xc1 = min(max(x1, 0), WW - 1);
        float r00 = (vy0 && vx0) ? (1.f - wy) * (1.f - wx) : 0.f;
        float r01 = (vy0 && vx1) ? (1.f - wy) * wx : 0.f;
        float r10 = (vy1 && vx0) ? wy * (1.f - wx) : 0.f;
        float r11 = (vy1 && vx1) ? wy * wx : 0.f;
        int i00 = (yc0 * WW + xc0) * 8, i01 = (yc0 * WW + xc1) * 8;
        int i10 = (yc1 * WW + xc0) * 8, i11 = (yc1 * WW + xc1) * 8;

        // all 8 gathers issued together (4 corners x 2 channel-half planes)
        U4 g00[2], g01[2], g10[2], g11[2];
#pragma unroll
        for (int ks = 0; ks < 2; ++ks) {
            const short* xk = xq + (size_t)ks * 4 * PS;
            g00[ks].v = *(const uint4*)(xk + i00);
            g01[ks].v = *(const uint4*)(xk + i01);
            g10[ks].v = *(const uint4*)(xk + i10);
            g11[ks].v = *(const uint4*)(xk + i11);
        }

        um += r00 * mb[i00 >> 3] + r01 * mb[i01 >> 3]
            + r10 * mb[i10 >> 3] + r11 * mb[i11 >> 3];

        float w00 = r00 * m, w01 = r01 * m, w10 = r10 * m, w11 = r11 * m;

#pragma unroll
        for (int ks = 0; ks < 2; ++ks) {
            union { bf16x8 s8; unsigned u[4]; } A;
#pragma unroll
            for (int q = 0; q < 4; ++q) {
                unsigned d00 = g00[ks].a[q], d01 = g01[ks].a[q];
                unsigned d10 = g10[ks].a[q], d11 = g11[ks].a[q];
                float vlo = fmaf(w00, bflo(d00), fmaf(w01, bflo(d01),
                            fmaf(w10, bflo(d10), w11 * bflo(d11))));
                float vhi = fmaf(w00, bfhi(d00), fmaf(w01, bfhi(d01),
                            fmaf(w10, bfhi(d10), w11 * bfhi(d11))));
                A.u[q] = cvtpk(vlo, vhi);
            }
            const bf16x8* wbk = wd + ((ks * 9 + k) * 4) * 64 + lane;
            bf16x8 B0 = wbk[0];
            bf16x8 B1 = wbk[64];
            bf16x8 B2 = wbk[128];
            bf16x8 B3 = wbk[192];
            acc0 = __builtin_amdgcn_mfma_f32_16x16x32_bf16(A.s8, B0, acc0, 0, 0, 0);
            acc1 = __builtin_amdgcn_mfma_f32_16x16x32_bf16(A.s8, B1, acc1, 0, 0, 0);
            acc2 = __builtin_amdgcn_mfma_f32_16x16x32_bf16(A.s8, B2, acc2, 0, 0, 0);
            acc3 = __builtin_amdgcn_mfma_f32_16x16x32_bf16(A.s8, B3, acc3, 0, 0, 0);
        }
    }

    um = fminf(fmaxf(64.f * um, 0.f), 1.f);
    if (lane < 16) upd[g0 + lane] = um;

    int oc = lane & 15;
    int pr0 = lg * 4;
    float u[4];
#pragma unroll
    for (int rr = 0; rr < 4; ++rr) u[rr] = __shfl(um, pr0 + rr, 64);

#define STORE_NT(ACC, NT)                                                     \
    {                                                                         \
        float bo = bias[(NT) * 16 + oc];                                      \
        _Pragma("unroll")                                                     \
        for (int rr = 0; rr < 4; ++rr) {                                      \
            int gg = g0 + pr0 + rr;                                           \
            int bb = gg >> 14;                                                \
            int pp = gg & (HWSZ - 1);                                         \
            out[((size_t)(bb * 64 + (NT) * 16 + oc)) * HWSZ + pp] =           \
                (ACC[rr] + bo) * u[rr];                                       \
        }                                                                     \
    }
    STORE_NT(acc0, 0)
    STORE_NT(acc1, 1)
    STORE_NT(acc2, 2)
    STORE_NT(acc3, 3)
#undef STORE_NT
}

extern "C" void kernel_launch(void* const* d_in, const int* in_sizes, int n_in,
                              void* d_out, int out_size, void* d_ws, size_t ws_size,
                              hipStream_t stream) {
    const float* input    = (const float*)d_in[0];
    const float* mask_in  = (const float*)d_in[1];
    const float* weight   = (const float*)d_in[2];
    const float* bias     = (const float*)d_in[3];
    const float* offset_w = (const float*)d_in[4];
    const float* offset_b = (const float*)d_in[5];
    const float* mask_w   = (const float*)d_in[6];
    const float* mask_b   = (const float*)d_in[7];

    float* out = (float*)d_out;
    float* upd = out + (size_t)NB * 64 * HWSZ;

    float* ws     = (float*)d_ws;
    float* off_px = ws;                                   // 65536*32 f32 = 8 MB
    short* wd2    = (short*)(off_px + (size_t)65536*32);  // 36,864 bf16
    short* wc2    = wd2 + 36864;                          // 27,648 bf16
    short* xt2    = wc2 + 27648;                          // 4*12*16384*8 bf16 = 12.6 MB

    hipLaunchKernelGGL(prep_kernel, dim3(1168), dim3(256), 0, stream,
                       input, mask_in, weight, offset_w, mask_w, xt2, wd2, wc2);
    hipLaunchKernelGGL(conv_offset_mfma, dim3(1024), dim3(256), 0, stream,
                       xt2, (const bf16x8*)wc2, offset_b, mask_b, off_px);
    hipLaunchKernelGGL(deform_main_mfma, dim3(1024), dim3(256), 0, stream,
                       xt2, off_px, mask_in, (const bf16x8*)wd2, bias, out, upd);
}

// Round 11
// 51.296 us; speedup vs baseline: 1.7276x; 1.3345x over previous
//
#include <hip/hip_runtime.h>

#define HH 128
#define WW 128
#define HWSZ (HH*WW)
#define NB 4
#define KK 9
#define PS (HWSZ*8)          // plane stride in shorts: 16384 px * 8 ch
#define IMS (12*PS)          // image stride in shorts: 12 channel-blocks

typedef _Float16 half8 __attribute__((ext_vector_type(8)));
typedef _Float16 h2    __attribute__((ext_vector_type(2)));
typedef float f32x4    __attribute__((ext_vector_type(4)));

union U4 { uint4 v; unsigned a[4]; };
union HU { unsigned u; h2 h; };

__device__ __forceinline__ short f2h(float f) {
    union { _Float16 h; short s; } u; u.h = (_Float16)f; return u.s;
}

// ---------------- prep: channel-block-planar f16 transpose + weight repack ----------------
// xt2: [b][cb(12)][pixel(16384)][8ch] f16. cb0-7 = input ch 0..63, cb8 = {mask,0...}, cb9-11 = 0
// wd2: deform B frags [ks(2)][tap(9)][nt(4)][lane(64)][8] f16 (36,864)
// wc2: conv   B frags [ks(3)][tap(9)][nt(2)][lane(64)][8] f16 (27,648); ks=2 = mask channel
__global__ __launch_bounds__(256) void prep_kernel(
    const float* __restrict__ input,
    const float* __restrict__ mask_in,
    const float* __restrict__ weight,
    const float* __restrict__ offset_w,
    const float* __restrict__ mask_w,
    short* __restrict__ xt2,
    short* __restrict__ wd2,
    short* __restrict__ wc2)
{
    __shared__ short lds[64 * 104];
    int bid = blockIdx.x;
    if (bid < 1024) {
        int wg = ((bid & 7) << 7) | (bid >> 3);   // XCD band swizzle
        int g0 = wg * 64;
        int b  = g0 >> 14;
        int p0 = g0 & (HWSZ - 1);
        int px = threadIdx.x & 63;
        int cq = threadIdx.x >> 6;
#pragma unroll
        for (int it = 0; it < 24; ++it) {
            int c = it * 4 + cq;
            float v;
            if (c < 64)       v = input[((size_t)(b * 64 + c)) * HWSZ + p0 + px];
            else if (c == 64) v = mask_in[(size_t)b * HWSZ + p0 + px];
            else              v = 0.f;
            lds[px * 104 + c] = f2h(v);
        }
        __syncthreads();
#pragma unroll
        for (int it = 0; it < 3; ++it) {
            int idx = it * 256 + threadIdx.x;
            if (idx < 768) {
                int ppx = idx / 12, cb = idx - ppx * 12;
                uint4 v = *(const uint4*)&lds[ppx * 104 + cb * 8];
                *(uint4*)&xt2[(size_t)b * IMS + (size_t)cb * PS + (size_t)(p0 + ppx) * 8] = v;
            }
        }
    } else {
        int idx = (bid - 1024) * 256 + threadIdx.x;   // 0..36863
        if (idx < 36864) {
            int j = idx & 7, l = (idx >> 3) & 63, f = idx >> 9;
            int nt = f & 3, t9 = f >> 2;
            int k = t9 % 9, ks = t9 / 9;
            int o = nt * 16 + (l & 15);
            int c = ks * 32 + ((l >> 4) & 3) * 8 + j;
            wd2[idx] = f2h(weight[(o * 64 + c) * 9 + k]);
        }
        if (idx < 27648) {
            int j = idx & 7, l = (idx >> 3) & 63, f = idx >> 9;
            int nt = f & 1, t9 = f >> 1;
            int k = t9 % 9, ks = t9 / 9;
            int o = nt * 16 + (l & 15);
            int c = ks * 32 + ((l >> 4) & 3) * 8 + j;
            float v = 0.f;
            if (c <= 64) {
                if (o < 18)      v = offset_w[(o * 65 + c) * 9 + k];
                else if (o < 27) v = mask_w[((o - 18) * 65 + c) * 9 + k];
            }
            wc2[idx] = f2h(v);
        }
    }
}

// ---------------- conv (65ch in, 27ch out, 3x3, pad 1): f16 MFMA, planar coalesced A ----------------
// off_px: [NB*HWSZ][32] f32: 0..17 offsets (dy/dx), 18..26 sigmoid(mask)
__global__ __launch_bounds__(256, 4) void conv_offset_mfma(
    const short* __restrict__ xt2, const half8* __restrict__ wc,
    const float* __restrict__ offset_b, const float* __restrict__ mask_b,
    float* __restrict__ off_px)
{
    int bid = blockIdx.x;
    int wg = ((bid & 7) << 7) | (bid >> 3);
    int wid = threadIdx.x >> 6, lane = threadIdx.x & 63;
    int r = lane & 15, lg = lane >> 4;
    int g0 = wg * 64 + wid * 16;
    int gp = g0 + r;
    int b = gp >> 14, p = gp & (HWSZ - 1);
    int i = p >> 7, j = p & 127;
    const short* xq = xt2 + (size_t)b * IMS + (size_t)lg * PS;

    f32x4 acc0 = {0,0,0,0}, acc1 = {0,0,0,0};

#pragma unroll
    for (int t = 0; t < 9; ++t) {
        int yy = i + t / 3 - 1, xx = j + t % 3 - 1;
        bool v = ((unsigned)yy < HH) && ((unsigned)xx < WW);
        int nb = (v ? yy * WW + xx : 0) * 8;
        union { half8 s8; uint4 u; } A[3];
#pragma unroll
        for (int ks = 0; ks < 3; ++ks) {
            A[ks].u = *(const uint4*)(xq + (size_t)ks * 4 * PS + nb);
            if (!v) { A[ks].u.x = 0; A[ks].u.y = 0; A[ks].u.z = 0; A[ks].u.w = 0; }
        }
#pragma unroll
        for (int ks = 0; ks < 3; ++ks) {
            const half8* wck = wc + ((ks * 9 + t) * 2) * 64 + lane;
            half8 B0 = wck[0];
            half8 B1 = wck[64];
            acc0 = __builtin_amdgcn_mfma_f32_16x16x32_f16(A[ks].s8, B0, acc0, 0, 0, 0);
            acc1 = __builtin_amdgcn_mfma_f32_16x16x32_f16(A[ks].s8, B1, acc1, 0, 0, 0);
        }
    }

    int oc = lane & 15, pr0 = lg * 4;
#pragma unroll
    for (int rr = 0; rr < 4; ++rr) {
        int gpix = g0 + pr0 + rr;
        float* orow = off_px + (size_t)gpix * 32;
        orow[oc] = acc0[rr] + offset_b[oc];
        int oc2 = 16 + oc;
        if (oc2 < 18) {
            orow[oc2] = acc1[rr] + offset_b[oc2];
        } else if (oc2 < 27) {
            float z = acc1[rr] + mask_b[oc2 - 18];
            orow[oc2] = 1.f / (1.f + __expf(-z));
        }
    }
}

// ---------------- main deformable conv: LDS-tile gathers + f16 pk-blend + MFMA ----------------
// Block = 64 pixels of one row (row i, cols j0b..j0b+63). LDS tile: rows i-2..i+2, cols j0b-2..j0b+65.
__global__ __launch_bounds__(256, 3) void deform_main_mfma(
    const short* __restrict__ xt2, const float* __restrict__ off_px,
    const float* __restrict__ mask_in, const half8* __restrict__ wd,
    const float* __restrict__ bias,
    float* __restrict__ out, float* __restrict__ upd)
{
    __shared__ short xsm[8 * 5 * 68 * 8];   // 43,520 B
    __shared__ float msm[5 * 68];           //  1,360 B

    int bid = blockIdx.x;
    int wg = ((bid & 7) << 7) | (bid >> 3);
    int wid = threadIdx.x >> 6, lane = threadIdx.x & 63;
    int r = lane & 15, lg = lane >> 4;
    int gblk = wg * 64;
    int b = gblk >> 14;
    int pblk = gblk & (HWSZ - 1);
    int ib = pblk >> 7, j0b = pblk & 127;
    int g0 = gblk + wid * 16;
    int gp = g0 + r;
    int p = gp & (HWSZ - 1);
    int i = p >> 7, j = p & 127;
    const short* xq = xt2 + (size_t)b * IMS + (size_t)lg * PS;
    const float* mb = mask_in + (size_t)b * HWSZ;

    // ---- stage tile: 8 planes x 5 rows x 68 cols x 8ch (f16) + mask 5x68 (f32) ----
    {
        const short* xg = xt2 + (size_t)b * IMS;
        for (int idx = threadIdx.x; idx < 2720; idx += 256) {
            int rb = idx / 68, tc = idx - rb * 68;
            int cb = rb / 5,  tr = rb - cb * 5;
            int row_g = min(max(ib - 2 + tr, 0), HH - 1);
            int col_g = min(max(j0b - 2 + tc, 0), WW - 1);
            uint4 v = *(const uint4*)&xg[(size_t)cb * PS + (size_t)(row_g * WW + col_g) * 8];
            *(uint4*)&xsm[(size_t)idx * 8] = v;
        }
        for (int idx = threadIdx.x; idx < 340; idx += 256) {
            int tr = idx / 68, tc = idx - tr * 68;
            int row_g = min(max(ib - 2 + tr, 0), HH - 1);
            int col_g = min(max(j0b - 2 + tc, 0), WW - 1);
            msm[idx] = mb[row_g * WW + col_g];
        }
    }
    __syncthreads();

    float ov[28];
    {
        const float4* op = (const float4*)(off_px + (size_t)gp * 32);
#pragma unroll
        for (int q = 0; q < 7; ++q) {
            float4 t = op[q];
            ov[4*q+0] = t.x; ov[4*q+1] = t.y; ov[4*q+2] = t.z; ov[4*q+3] = t.w;
        }
    }

    f32x4 acc0 = {0,0,0,0}, acc1 = {0,0,0,0}, acc2 = {0,0,0,0}, acc3 = {0,0,0,0};
    float um = 0.f;

#pragma unroll
    for (int k = 0; k < KK; ++k) {
        float dy = ov[2*k], dx = ov[2*k+1], m = ov[18+k];
        float py  = dy + (float)(k / 3 + i - 1);
        float pxx = dx + (float)(k % 3 + j - 1);
        float fy = floorf(py), fx = floorf(pxx);
        float wy = py - fy, wx = pxx - fx;
        int y0 = (int)fy, x0 = (int)fx;
        int y1 = y0 + 1, x1 = x0 + 1;
        bool vy0 = (unsigned)y0 < HH, vy1 = (unsigned)y1 < HH;
        bool vx0 = (unsigned)x0 < WW, vx1 = (unsigned)x1 < WW;
        int yc0 = min(max(y0, 0), HH - 1), yc1 = min(max(y1, 0), HH - 1);
        int xc0 = min(max(x0, 0), WW - 1), xc1 = min(max(x1, 0), WW - 1);
        float r00 = (vy0 && vx0) ? (1.f - wy) * (1.f - wx) : 0.f;
        float r01 = (vy0 && vx1) ? (1.f - wy) * wx : 0.f;
        float r10 = (vy1 && vx0) ? wy * (1.f - wx) : 0.f;
        float r11 = (vy1 && vx1) ? wy * wx : 0.f;

        // tile coords (block-relative)
        int tr0 = yc0 - ib + 2, tr1 = yc1 - ib + 2;
        int tc0 = xc0 - j0b + 2, tc1 = xc1 - j0b + 2;
        bool in00 = ((unsigned)tr0 < 5u) & ((unsigned)tc0 < 68u);
        bool in01 = ((unsigned)tr0 < 5u) & ((unsigned)tc1 < 68u);
        bool in10 = ((unsigned)tr1 < 5u) & ((unsigned)tc0 < 68u);
        bool in11 = ((unsigned)tr1 < 5u) & ((unsigned)tc1 < 68u);
        int trc0 = min(max(tr0, 0), 4), trc1 = min(max(tr1, 0), 4);
        int tcc0 = min(max(tc0, 0), 67), tcc1 = min(max(tc1, 0), 67);
        int l00 = (trc0 * 68 + tcc0), l01 = (trc0 * 68 + tcc1);
        int l10 = (trc1 * 68 + tcc0), l11 = (trc1 * 68 + tcc1);

        U4 g00[2], g01[2], g10[2], g11[2];
#pragma unroll
        for (int ks = 0; ks < 2; ++ks) {
            const short* xs = xsm + (size_t)(ks * 4 + lg) * (5 * 68 * 8);
            g00[ks].v = *(const uint4*)(xs + l00 * 8);
            g01[ks].v = *(const uint4*)(xs + l01 * 8);
            g10[ks].v = *(const uint4*)(xs + l10 * 8);
            g11[ks].v = *(const uint4*)(xs + l11 * 8);
        }
        float m00 = msm[l00], m01 = msm[l01], m10 = msm[l10], m11 = msm[l11];

        if (!__all(in00 & in01 & in10 & in11)) {
            int p00 = yc0 * WW + xc0, p01 = yc0 * WW + xc1;
            int p10 = yc1 * WW + xc0, p11 = yc1 * WW + xc1;
            if (!in00) {
                g00[0].v = *(const uint4*)(xq + (size_t)p00 * 8);
                g00[1].v = *(const uint4*)(xq + 4 * PS + (size_t)p00 * 8);
                m00 = mb[p00];
            }
            if (!in01) {
                g01[0].v = *(const uint4*)(xq + (size_t)p01 * 8);
                g01[1].v = *(const uint4*)(xq + 4 * PS + (size_t)p01 * 8);
                m01 = mb[p01];
            }
            if (!in10) {
                g10[0].v = *(const uint4*)(xq + (size_t)p10 * 8);
                g10[1].v = *(const uint4*)(xq + 4 * PS + (size_t)p10 * 8);
                m10 = mb[p10];
            }
            if (!in11) {
                g11[0].v = *(const uint4*)(xq + (size_t)p11 * 8);
                g11[1].v = *(const uint4*)(xq + 4 * PS + (size_t)p11 * 8);
                m11 = mb[p11];
            }
        }

        um += r00 * m00 + r01 * m01 + r10 * m10 + r11 * m11;

        float w00 = r00 * m, w01 = r01 * m, w10 = r10 * m, w11 = r11 * m;
        h2 w00h = { (_Float16)w00, (_Float16)w00 };
        h2 w01h = { (_Float16)w01, (_Float16)w01 };
        h2 w10h = { (_Float16)w10, (_Float16)w10 };
        h2 w11h = { (_Float16)w11, (_Float16)w11 };

#pragma unroll
        for (int ks = 0; ks < 2; ++ks) {
            union { half8 s8; unsigned u[4]; } A;
#pragma unroll
            for (int q = 0; q < 4; ++q) {
                HU a00, a01, a10, a11, res;
                a00.u = g00[ks].a[q]; a01.u = g01[ks].a[q];
                a10.u = g10[ks].a[q]; a11.u = g11[ks].a[q];
                h2 acc = a00.h * w00h;
                acc = a01.h * w01h + acc;
                acc = a10.h * w10h + acc;
                acc = a11.h * w11h + acc;
                res.h = acc;
                A.u[q] = res.u;
            }
            const half8* wbk = wd + ((ks * 9 + k) * 4) * 64 + lane;
            half8 B0 = wbk[0];
            half8 B1 = wbk[64];
            half8 B2 = wbk[128];
            half8 B3 = wbk[192];
            acc0 = __builtin_amdgcn_mfma_f32_16x16x32_f16(A.s8, B0, acc0, 0, 0, 0);
            acc1 = __builtin_amdgcn_mfma_f32_16x16x32_f16(A.s8, B1, acc1, 0, 0, 0);
            acc2 = __builtin_amdgcn_mfma_f32_16x16x32_f16(A.s8, B2, acc2, 0, 0, 0);
            acc3 = __builtin_amdgcn_mfma_f32_16x16x32_f16(A.s8, B3, acc3, 0, 0, 0);
        }
    }

    um = fminf(fmaxf(64.f * um, 0.f), 1.f);
    if (lane < 16) upd[g0 + lane] = um;

    int oc = lane & 15;
    int pr0 = lg * 4;
    float u[4];
#pragma unroll
    for (int rr = 0; rr < 4; ++rr) u[rr] = __shfl(um, pr0 + rr, 64);

#define STORE_NT(ACC, NT)                                                     \
    {                                                                         \
        float bo = bias[(NT) * 16 + oc];                                      \
        _Pragma("unroll")                                                     \
        for (int rr = 0; rr < 4; ++rr) {                                      \
            int gg = g0 + pr0 + rr;                                           \
            int bb = gg >> 14;                                                \
            int pp = gg & (HWSZ - 1);                                         \
            out[((size_t)(bb * 64 + (NT) * 16 + oc)) * HWSZ + pp] =           \
                (ACC[rr] + bo) * u[rr];                                       \
        }                                                                     \
    }
    STORE_NT(acc0, 0)
    STORE_NT(acc1, 1)
    STORE_NT(acc2, 2)
    STORE_NT(acc3, 3)
#undef STORE_NT
}

extern "C" void kernel_launch(void* const* d_in, const int* in_sizes, int n_in,
                              void* d_out, int out_size, void* d_ws, size_t ws_size,
                              hipStream_t stream) {
    const float* input    = (const float*)d_in[0];
    const float* mask_in  = (const float*)d_in[1];
    const float* weight   = (const float*)d_in[2];
    const float* bias     = (const float*)d_in[3];
    const float* offset_w = (const float*)d_in[4];
    const float* offset_b = (const float*)d_in[5];
    const float* mask_w   = (const float*)d_in[6];
    const float* mask_b   = (const float*)d_in[7];

    float* out = (float*)d_out;
    float* upd = out + (size_t)NB * 64 * HWSZ;

    float* ws     = (float*)d_ws;
    float* off_px = ws;                                   // 65536*32 f32 = 8 MB
    short* wd2    = (short*)(off_px + (size_t)65536*32);  // 36,864 f16
    short* wc2    = wd2 + 36864;                          // 27,648 f16
    short* xt2    = wc2 + 27648;                          // 4*12*16384*8 f16 = 12.6 MB

    hipLaunchKernelGGL(prep_kernel, dim3(1168), dim3(256), 0, stream,
                       input, mask_in, weight, offset_w, mask_w, xt2, wd2, wc2);
    hipLaunchKernelGGL(conv_offset_mfma, dim3(1024), dim3(256), 0, stream,
                       xt2, (const half8*)wc2, offset_b, mask_b, off_px);
    hipLaunchKernelGGL(deform_main_mfma, dim3(1024), dim3(256), 0, stream,
                       xt2, off_px, mask_in, (const half8*)wd2, bias, out, upd);
}

// Round 12
// 43.172 us; speedup vs baseline: 2.0527x; 1.1882x over previous
//
#include <hip/hip_runtime.h>

#define HH 128
#define WW 128
#define HWSZ (HH*WW)
#define NB 4
#define KK 9
#define PS (HWSZ*8)          // plane stride in shorts: 16384 px * 8 ch
#define IMS (12*PS)          // image stride in shorts: 12 channel-blocks

typedef _Float16 half8 __attribute__((ext_vector_type(8)));
typedef _Float16 h2    __attribute__((ext_vector_type(2)));
typedef float f32x4    __attribute__((ext_vector_type(4)));

union U4 { uint4 v; unsigned a[4]; };
union HU { unsigned u; h2 h; };

__device__ __forceinline__ short f2h(float f) {
    union { _Float16 h; short s; } u; u.h = (_Float16)f; return u.s;
}
__device__ __forceinline__ void gl_lds16(const short* g, short* l) {
    __builtin_amdgcn_global_load_lds(
        (const __attribute__((address_space(1))) void*)g,
        (__attribute__((address_space(3))) void*)l, 16, 0, 0);
}
__device__ __forceinline__ void gl_lds4(const float* g, float* l) {
    __builtin_amdgcn_global_load_lds(
        (const __attribute__((address_space(1))) void*)g,
        (__attribute__((address_space(3))) void*)l, 4, 0, 0);
}

// ---------------- prep: channel-block-planar f16 transpose + weight repack ----------------
// xt2: [b][cb(12)][pixel(16384)][8ch] f16. cb0-7 = input ch 0..63, cb8 = {mask,0...}, cb9-11 = 0
// wd2: deform B frags [ks(2)][tap(9)][nt(4)][lane(64)][8] f16 (36,864)
// wc2: conv   B frags [ks(3)][tap(9)][nt(2)][lane(64)][8] f16 (27,648); ks=2 = mask channel
__global__ __launch_bounds__(256) void prep_kernel(
    const float* __restrict__ input,
    const float* __restrict__ mask_in,
    const float* __restrict__ weight,
    const float* __restrict__ offset_w,
    const float* __restrict__ mask_w,
    short* __restrict__ xt2,
    short* __restrict__ wd2,
    short* __restrict__ wc2)
{
    __shared__ short lds[64 * 104];
    int bid = blockIdx.x;
    if (bid < 1024) {
        int wg = ((bid & 7) << 7) | (bid >> 3);   // XCD band swizzle
        int g0 = wg * 64;
        int b  = g0 >> 14;
        int p0 = g0 & (HWSZ - 1);
        int px = threadIdx.x & 63;
        int cq = threadIdx.x >> 6;
#pragma unroll
        for (int it = 0; it < 24; ++it) {
            int c = it * 4 + cq;
            float v;
            if (c < 64)       v = input[((size_t)(b * 64 + c)) * HWSZ + p0 + px];
            else if (c == 64) v = mask_in[(size_t)b * HWSZ + p0 + px];
            else              v = 0.f;
            lds[px * 104 + c] = f2h(v);
        }
        __syncthreads();
#pragma unroll
        for (int it = 0; it < 3; ++it) {
            int idx = it * 256 + threadIdx.x;
            if (idx < 768) {
                int ppx = idx / 12, cb = idx - ppx * 12;
                uint4 v = *(const uint4*)&lds[ppx * 104 + cb * 8];
                *(uint4*)&xt2[(size_t)b * IMS + (size_t)cb * PS + (size_t)(p0 + ppx) * 8] = v;
            }
        }
    } else {
        int idx = (bid - 1024) * 256 + threadIdx.x;   // 0..36863
        if (idx < 36864) {
            int j = idx & 7, l = (idx >> 3) & 63, f = idx >> 9;
            int nt = f & 3, t9 = f >> 2;
            int k = t9 % 9, ks = t9 / 9;
            int o = nt * 16 + (l & 15);
            int c = ks * 32 + ((l >> 4) & 3) * 8 + j;
            wd2[idx] = f2h(weight[(o * 64 + c) * 9 + k]);
        }
        if (idx < 27648) {
            int j = idx & 7, l = (idx >> 3) & 63, f = idx >> 9;
            int nt = f & 1, t9 = f >> 1;
            int k = t9 % 9, ks = t9 / 9;
            int o = nt * 16 + (l & 15);
            int c = ks * 32 + ((l >> 4) & 3) * 8 + j;
            float v = 0.f;
            if (c <= 64) {
                if (o < 18)      v = offset_w[(o * 65 + c) * 9 + k];
                else if (o < 27) v = mask_w[((o - 18) * 65 + c) * 9 + k];
            }
            wc2[idx] = f2h(v);
        }
    }
}

// ---------------- fused conv + deform ----------------
// Block = 64 pixels of one row. Phase 0: async-stage x-tile (8 planes x 5x68 x 8ch f16)
// + mask tile (5x68 f32). Phase 1: offset/mask conv (A global-planar) -> offsm LDS.
// Phase 2: deform from LDS tile. Phase 3: transpose epilogue -> coalesced NCHW stores.
__global__ __launch_bounds__(256, 3) void fused_conv_deform(
    const short* __restrict__ xt2, const float* __restrict__ mask_in,
    const half8* __restrict__ wc, const half8* __restrict__ wd,
    const float* __restrict__ offset_b, const float* __restrict__ mask_b,
    const float* __restrict__ bias,
    float* __restrict__ out, float* __restrict__ upd)
{
    __shared__ short xsm[8 * 5 * 68 * 8];   // 43,520 B (reused as outsm in epilogue)
    __shared__ float msm[5 * 68];           //  1,360 B
    __shared__ float offsm[64 * 28];        //  7,168 B

    int bid = blockIdx.x;
    int wg = ((bid & 7) << 7) | (bid >> 3);
    int wid = threadIdx.x >> 6, lane = threadIdx.x & 63;
    int r = lane & 15, lg = lane >> 4;
    int gblk = wg * 64;
    int b = gblk >> 14;
    int pblk = gblk & (HWSZ - 1);
    int ib = pblk >> 7, j0b = pblk & 127;
    int g0 = gblk + wid * 16;
    int gp = g0 + r;
    int p = gp & (HWSZ - 1);
    int i = p >> 7, j = p & 127;
    const short* xq = xt2 + (size_t)b * IMS + (size_t)lg * PS;
    const float* mb = mask_in + (size_t)b * HWSZ;

    // ---- Phase 0: async staging (no VGPR round trip, drains at the barrier) ----
    {
        const short* xg = xt2 + (size_t)b * IMS;
#pragma unroll
        for (int it = 0; it < 11; ++it) {
            int idx = it * 256 + threadIdx.x;
            if (idx < 2720) {
                int rb = idx / 68, tc = idx - rb * 68;
                int cb = rb / 5,  tr = rb - cb * 5;
                int row_g = min(max(ib - 2 + tr, 0), HH - 1);
                int col_g = min(max(j0b - 2 + tc, 0), WW - 1);
                gl_lds16(&xg[(size_t)cb * PS + (size_t)(row_g * WW + col_g) * 8],
                         &xsm[idx * 8]);
            }
        }
#pragma unroll
        for (int it = 0; it < 2; ++it) {
            int idx = it * 256 + threadIdx.x;
            if (idx < 340) {
                int tr = idx / 68, tc = idx - tr * 68;
                int row_g = min(max(ib - 2 + tr, 0), HH - 1);
                int col_g = min(max(j0b - 2 + tc, 0), WW - 1);
                gl_lds4(&mb[row_g * WW + col_g], &msm[idx]);
            }
        }
    }

    // ---- Phase 1: offset/mask conv (A from global planar xt2) ----
    {
        f32x4 ca0 = {0,0,0,0}, ca1 = {0,0,0,0};
#pragma unroll
        for (int t = 0; t < 9; ++t) {
            int yy = i + t / 3 - 1, xx = j + t % 3 - 1;
            bool v = ((unsigned)yy < HH) && ((unsigned)xx < WW);
            int nb = (v ? yy * WW + xx : 0) * 8;
            union { half8 s8; uint4 u; } A[3];
#pragma unroll
            for (int ks = 0; ks < 3; ++ks) {
                A[ks].u = *(const uint4*)(xq + (size_t)ks * 4 * PS + nb);
                if (!v) { A[ks].u.x = 0; A[ks].u.y = 0; A[ks].u.z = 0; A[ks].u.w = 0; }
            }
#pragma unroll
            for (int ks = 0; ks < 3; ++ks) {
                const half8* wck = wc + ((ks * 9 + t) * 2) * 64 + lane;
                half8 B0 = wck[0];
                half8 B1 = wck[64];
                ca0 = __builtin_amdgcn_mfma_f32_16x16x32_f16(A[ks].s8, B0, ca0, 0, 0, 0);
                ca1 = __builtin_amdgcn_mfma_f32_16x16x32_f16(A[ks].s8, B1, ca1, 0, 0, 0);
            }
        }
        int oc = lane & 15, pr0 = lg * 4;
#pragma unroll
        for (int rr = 0; rr < 4; ++rr) {
            int pxl = wid * 16 + pr0 + rr;
            offsm[pxl * 28 + oc] = ca0[rr] + offset_b[oc];
            int oc2 = 16 + oc;
            if (oc2 < 18) {
                offsm[pxl * 28 + oc2] = ca1[rr] + offset_b[oc2];
            } else if (oc2 < 27) {
                float z = ca1[rr] + mask_b[oc2 - 18];
                offsm[pxl * 28 + oc2] = 1.f / (1.f + __expf(-z));
            }
        }
    }
    asm volatile("s_waitcnt vmcnt(0)" ::: "memory");
    __syncthreads();

    // ---- Phase 2: deformable conv from LDS tile ----
    float ov[28];
    {
        int pxl = wid * 16 + r;
#pragma unroll
        for (int q = 0; q < 7; ++q) {
            float4 t = *(const float4*)&offsm[pxl * 28 + q * 4];
            ov[4*q+0] = t.x; ov[4*q+1] = t.y; ov[4*q+2] = t.z; ov[4*q+3] = t.w;
        }
    }

    f32x4 acc0 = {0,0,0,0}, acc1 = {0,0,0,0}, acc2 = {0,0,0,0}, acc3 = {0,0,0,0};
    float um = 0.f;

#pragma unroll
    for (int k = 0; k < KK; ++k) {
        float dy = ov[2*k], dx = ov[2*k+1], m = ov[18+k];
        float py  = dy + (float)(k / 3 + i - 1);
        float pxx = dx + (float)(k % 3 + j - 1);
        float fy = floorf(py), fx = floorf(pxx);
        float wy = py - fy, wx = pxx - fx;
        int y0 = (int)fy, x0 = (int)fx;
        int y1 = y0 + 1, x1 = x0 + 1;
        bool vy0 = (unsigned)y0 < HH, vy1 = (unsigned)y1 < HH;
        bool vx0 = (unsigned)x0 < WW, vx1 = (unsigned)x1 < WW;
        int yc0 = min(max(y0, 0), HH - 1), yc1 = min(max(y1, 0), HH - 1);
        int xc0 = min(max(x0, 0), WW - 1), xc1 = min(max(x1, 0), WW - 1);
        float r00 = (vy0 && vx0) ? (1.f - wy) * (1.f - wx) : 0.f;
        float r01 = (vy0 && vx1) ? (1.f - wy) * wx : 0.f;
        float r10 = (vy1 && vx0) ? wy * (1.f - wx) : 0.f;
        float r11 = (vy1 && vx1) ? wy * wx : 0.f;

        int tr0 = yc0 - ib + 2, tr1 = yc1 - ib + 2;
        int tc0 = xc0 - j0b + 2, tc1 = xc1 - j0b + 2;
        bool in00 = ((unsigned)tr0 < 5u) & ((unsigned)tc0 < 68u);
        bool in01 = ((unsigned)tr0 < 5u) & ((unsigned)tc1 < 68u);
        bool in10 = ((unsigned)tr1 < 5u) & ((unsigned)tc0 < 68u);
        bool in11 = ((unsigned)tr1 < 5u) & ((unsigned)tc1 < 68u);
        int trc0 = min(max(tr0, 0), 4), trc1 = min(max(tr1, 0), 4);
        int tcc0 = min(max(tc0, 0), 67), tcc1 = min(max(tc1, 0), 67);
        int l00 = (trc0 * 68 + tcc0), l01 = (trc0 * 68 + tcc1);
        int l10 = (trc1 * 68 + tcc0), l11 = (trc1 * 68 + tcc1);

        U4 g00[2], g01[2], g10[2], g11[2];
#pragma unroll
        for (int ks = 0; ks < 2; ++ks) {
            const short* xs = xsm + (size_t)(ks * 4 + lg) * (5 * 68 * 8);
            g00[ks].v = *(const uint4*)(xs + l00 * 8);
            g01[ks].v = *(const uint4*)(xs + l01 * 8);
            g10[ks].v = *(const uint4*)(xs + l10 * 8);
            g11[ks].v = *(const uint4*)(xs + l11 * 8);
        }
        float m00 = msm[l00], m01 = msm[l01], m10 = msm[l10], m11 = msm[l11];

        if (!__all(in00 & in01 & in10 & in11)) {
            int p00 = yc0 * WW + xc0, p01 = yc0 * WW + xc1;
            int p10 = yc1 * WW + xc0, p11 = yc1 * WW + xc1;
            if (!in00) {
                g00[0].v = *(const uint4*)(xq + (size_t)p00 * 8);
                g00[1].v = *(const uint4*)(xq + 4 * PS + (size_t)p00 * 8);
                m00 = mb[p00];
            }
            if (!in01) {
                g01[0].v = *(const uint4*)(xq + (size_t)p01 * 8);
                g01[1].v = *(const uint4*)(xq + 4 * PS + (size_t)p01 * 8);
                m01 = mb[p01];
            }
            if (!in10) {
                g10[0].v = *(const uint4*)(xq + (size_t)p10 * 8);
                g10[1].v = *(const uint4*)(xq + 4 * PS + (size_t)p10 * 8);
                m10 = mb[p10];
            }
            if (!in11) {
                g11[0].v = *(const uint4*)(xq + (size_t)p11 * 8);
                g11[1].v = *(const uint4*)(xq + 4 * PS + (size_t)p11 * 8);
                m11 = mb[p11];
            }
        }

        um += r00 * m00 + r01 * m01 + r10 * m10 + r11 * m11;

        float w00 = r00 * m, w01 = r01 * m, w10 = r10 * m, w11 = r11 * m;
        h2 w00h = { (_Float16)w00, (_Float16)w00 };
        h2 w01h = { (_Float16)w01, (_Float16)w01 };
        h2 w10h = { (_Float16)w10, (_Float16)w10 };
        h2 w11h = { (_Float16)w11, (_Float16)w11 };

#pragma unroll
        for (int ks = 0; ks < 2; ++ks) {
            union { half8 s8; unsigned u[4]; } A;
#pragma unroll
            for (int q = 0; q < 4; ++q) {
                HU a00, a01, a10, a11, res;
                a00.u = g00[ks].a[q]; a01.u = g01[ks].a[q];
                a10.u = g10[ks].a[q]; a11.u = g11[ks].a[q];
                h2 acc = a00.h * w00h;
                acc = a01.h * w01h + acc;
                acc = a10.h * w10h + acc;
                acc = a11.h * w11h + acc;
                res.h = acc;
                A.u[q] = res.u;
            }
            const half8* wbk = wd + ((ks * 9 + k) * 4) * 64 + lane;
            half8 B0 = wbk[0];
            half8 B1 = wbk[64];
            half8 B2 = wbk[128];
            half8 B3 = wbk[192];
            acc0 = __builtin_amdgcn_mfma_f32_16x16x32_f16(A.s8, B0, acc0, 0, 0, 0);
            acc1 = __builtin_amdgcn_mfma_f32_16x16x32_f16(A.s8, B1, acc1, 0, 0, 0);
            acc2 = __builtin_amdgcn_mfma_f32_16x16x32_f16(A.s8, B2, acc2, 0, 0, 0);
            acc3 = __builtin_amdgcn_mfma_f32_16x16x32_f16(A.s8, B3, acc3, 0, 0, 0);
        }
    }

    um = fminf(fmaxf(64.f * um, 0.f), 1.f);
    if (lane < 16) upd[g0 + lane] = um;

    int oc = lane & 15;
    int pr0 = lg * 4;
    float u[4];
#pragma unroll
    for (int rr = 0; rr < 4; ++rr) u[rr] = __shfl(um, pr0 + rr, 64);

    // ---- Phase 3: transpose epilogue through LDS (reuse xsm), coalesced NCHW stores ----
    __syncthreads();                 // all xsm gathers done
    float* outsm = (float*)xsm;      // [64 px][stride 65] = 16,640 B
#define STORE_NT(ACC, NT)                                                     \
    {                                                                         \
        float bo = bias[(NT) * 16 + oc];                                      \
        _Pragma("unroll")                                                     \
        for (int rr = 0; rr < 4; ++rr) {                                      \
            int pxl = wid * 16 + pr0 + rr;                                    \
            outsm[pxl * 65 + (NT) * 16 + oc] = (ACC[rr] + bo) * u[rr];        \
        }                                                                     \
    }
    STORE_NT(acc0, 0)
    STORE_NT(acc1, 1)
    STORE_NT(acc2, 2)
    STORE_NT(acc3, 3)
#undef STORE_NT
    __syncthreads();
    {
        int ch = threadIdx.x >> 2, q = threadIdx.x & 3;
        float tmp[16];
#pragma unroll
        for (int mI = 0; mI < 16; ++mI)
            tmp[mI] = outsm[(q * 16 + mI) * 65 + ch];
        float4* dst = (float4*)(out + ((size_t)(b * 64 + ch)) * HWSZ + pblk + q * 16);
#pragma unroll
        for (int gq = 0; gq < 4; ++gq) {
            float4 v = { tmp[4*gq], tmp[4*gq+1], tmp[4*gq+2], tmp[4*gq+3] };
            dst[gq] = v;
        }
    }
}

extern "C" void kernel_launch(void* const* d_in, const int* in_sizes, int n_in,
                              void* d_out, int out_size, void* d_ws, size_t ws_size,
                              hipStream_t stream) {
    const float* input    = (const float*)d_in[0];
    const float* mask_in  = (const float*)d_in[1];
    const float* weight   = (const float*)d_in[2];
    const float* bias     = (const float*)d_in[3];
    const float* offset_w = (const float*)d_in[4];
    const float* offset_b = (const float*)d_in[5];
    const float* mask_w   = (const float*)d_in[6];
    const float* mask_b   = (const float*)d_in[7];

    float* out = (float*)d_out;
    float* upd = out + (size_t)NB * 64 * HWSZ;

    short* wd2 = (short*)d_ws;                 // 36,864 f16
    short* wc2 = wd2 + 36864;                  // 27,648 f16
    short* xt2 = wc2 + 27648;                  // 4*12*16384*8 f16 = 12.6 MB

    hipLaunchKernelGGL(prep_kernel, dim3(1168), dim3(256), 0, stream,
                       input, mask_in, weight, offset_w, mask_w, xt2, wd2, wc2);
    hipLaunchKernelGGL(fused_conv_deform, dim3(1024), dim3(256), 0, stream,
                       xt2, mask_in, (const half8*)wc2, (const half8*)wd2,
                       offset_b, mask_b, bias, out, upd);
}

// Round 13
// 39.732 us; speedup vs baseline: 2.2304x; 1.0866x over previous
//
#include <hip/hip_runtime.h>

#define HH 128
#define WW 128
#define HWSZ (HH*WW)
#define NB 4
#define KK 9
#define PS (HWSZ*8)          // plane stride in shorts: 16384 px * 8 ch
#define IMS (12*PS)          // image stride in shorts: 12 channel-blocks
#define TROWS 6
#define TCOLS 68
#define TPX (TROWS*TCOLS)    // 408 pixels per staged plane

typedef _Float16 half8 __attribute__((ext_vector_type(8)));
typedef _Float16 h2    __attribute__((ext_vector_type(2)));
typedef float f32x4    __attribute__((ext_vector_type(4)));

union U4 { uint4 v; unsigned a[4]; };
union HU { unsigned u; h2 h; };

__device__ __forceinline__ short f2h(float f) {
    union { _Float16 h; short s; } u; u.h = (_Float16)f; return u.s;
}
__device__ __forceinline__ void gl_lds16(const short* g, short* l) {
    __builtin_amdgcn_global_load_lds(
        (const __attribute__((address_space(1))) void*)g,
        (__attribute__((address_space(3))) void*)l, 16, 0, 0);
}
__device__ __forceinline__ void gl_lds4(const float* g, float* l) {
    __builtin_amdgcn_global_load_lds(
        (const __attribute__((address_space(1))) void*)g,
        (__attribute__((address_space(3))) void*)l, 4, 0, 0);
}

// ---------------- prep: channel-block-planar f16 transpose + weight repack ----------------
__global__ __launch_bounds__(256) void prep_kernel(
    const float* __restrict__ input,
    const float* __restrict__ mask_in,
    const float* __restrict__ weight,
    const float* __restrict__ offset_w,
    const float* __restrict__ mask_w,
    short* __restrict__ xt2,
    short* __restrict__ wd2,
    short* __restrict__ wc2)
{
    __shared__ short lds[64 * 104];
    int bid = blockIdx.x;
    if (bid < 1024) {
        int wg = ((bid & 7) << 7) | (bid >> 3);
        int g0 = wg * 64;
        int b  = g0 >> 14;
        int p0 = g0 & (HWSZ - 1);
        int px = threadIdx.x & 63;
        int cq = threadIdx.x >> 6;
#pragma unroll
        for (int it = 0; it < 24; ++it) {
            int c = it * 4 + cq;
            float v;
            if (c < 64)       v = input[((size_t)(b * 64 + c)) * HWSZ + p0 + px];
            else if (c == 64) v = mask_in[(size_t)b * HWSZ + p0 + px];
            else              v = 0.f;
            lds[px * 104 + c] = f2h(v);
        }
        __syncthreads();
#pragma unroll
        for (int it = 0; it < 3; ++it) {
            int idx = it * 256 + threadIdx.x;
            if (idx < 768) {
                int ppx = idx / 12, cb = idx - ppx * 12;
                uint4 v = *(const uint4*)&lds[ppx * 104 + cb * 8];
                *(uint4*)&xt2[(size_t)b * IMS + (size_t)cb * PS + (size_t)(p0 + ppx) * 8] = v;
            }
        }
    } else {
        int idx = (bid - 1024) * 256 + threadIdx.x;
        if (idx < 36864) {
            int j = idx & 7, l = (idx >> 3) & 63, f = idx >> 9;
            int nt = f & 3, t9 = f >> 2;
            int k = t9 % 9, ks = t9 / 9;
            int o = nt * 16 + (l & 15);
            int c = ks * 32 + ((l >> 4) & 3) * 8 + j;
            wd2[idx] = f2h(weight[(o * 64 + c) * 9 + k]);
        }
        if (idx < 27648) {
            int j = idx & 7, l = (idx >> 3) & 63, f = idx >> 9;
            int nt = f & 1, t9 = f >> 1;
            int k = t9 % 9, ks = t9 / 9;
            int o = nt * 16 + (l & 15);
            int c = ks * 32 + ((l >> 4) & 3) * 8 + j;
            float v = 0.f;
            if (c <= 64) {
                if (o < 18)      v = offset_w[(o * 65 + c) * 9 + k];
                else if (o < 27) v = mask_w[((o - 18) * 65 + c) * 9 + k];
            }
            wc2[idx] = f2h(v);
        }
    }
}

// ---------------- fused conv + deform: 128 px/block (2 rows x 64 cols), 32 px/wave ----------------
__global__ __launch_bounds__(256, 2) void fused_conv_deform(
    const short* __restrict__ xt2, const float* __restrict__ mask_in,
    const half8* __restrict__ wc, const half8* __restrict__ wd,
    const float* __restrict__ offset_b, const float* __restrict__ mask_b,
    const float* __restrict__ bias,
    float* __restrict__ out, float* __restrict__ upd)
{
    __shared__ short xsm[8 * TPX * 8];   // 52,224 B (reused as outsm in epilogue)
    __shared__ float msm[TPX];           //  1,632 B
    __shared__ short offsm[128 * 32];    //  8,192 B f16 (slots 0..26 used)

    int bid = blockIdx.x;
    int wg = ((bid & 7) << 6) | (bid >> 3);   // 512 blocks, XCD bands of 64
    int w = threadIdx.x >> 6, lane = threadIdx.x & 63;
    int r = lane & 15, lg = lane >> 4;
    int b = wg >> 7;
    int rem = wg & 127;
    int ib = (rem >> 1) * 2;          // row pair base
    int j0b = (rem & 1) * 64;         // column half
    int jw = j0b + w * 16;            // wave's column base
    int jj0 = jw + r;                 // this lane's column

    const short* xg = xt2 + (size_t)b * IMS;
    const short* xq = xg + (size_t)lg * PS;   // fallback base (ks0 plane lg)
    const float* mb = mask_in + (size_t)b * HWSZ;

    // ---- Phase 0: async-stage tile (8 planes x 6x68 x 8ch f16) + mask (6x68 f32) ----
#pragma unroll
    for (int cb = 0; cb < 8; ++cb) {
#pragma unroll
        for (int it = 0; it < 2; ++it) {
            int idx = it * 256 + threadIdx.x;
            if (idx < TPX) {
                int tr = idx / TCOLS, tc = idx - tr * TCOLS;
                int rg = min(max(ib - 2 + tr, 0), HH - 1);
                int cg = min(max(j0b - 2 + tc, 0), WW - 1);
                gl_lds16(&xg[(size_t)cb * PS + (size_t)(rg * WW + cg) * 8],
                         &xsm[(cb * TPX + idx) * 8]);
            }
        }
    }
#pragma unroll
    for (int it = 0; it < 2; ++it) {
        int idx = it * 256 + threadIdx.x;
        if (idx < TPX) {
            int tr = idx / TCOLS, tc = idx - tr * TCOLS;
            int rg = min(max(ib - 2 + tr, 0), HH - 1);
            int cg = min(max(j0b - 2 + tc, 0), WW - 1);
            gl_lds4(&mb[rg * WW + cg], &msm[idx]);
        }
    }
    asm volatile("s_waitcnt vmcnt(0)" ::: "memory");
    __syncthreads();

    // ---- Phase 1: offset/mask conv, A from LDS tile, 2 pixel-sets per wave ----
    {
        f32x4 ca00 = {0,0,0,0}, ca01 = {0,0,0,0};   // set0 nt0/nt1
        f32x4 ca10 = {0,0,0,0}, ca11 = {0,0,0,0};   // set1
#pragma unroll
        for (int t = 0; t < 9; ++t) {
            int dr = t / 3 - 1, dc = t % 3 - 1;
            // B frags for this tap (shared by both sets)
            const half8* wck = wc + (t * 2) * 64 + lane;
            half8 Bk0n0 = wck[0],        Bk0n1 = wck[64];
            half8 Bk1n0 = wck[9*2*64],   Bk1n1 = wck[9*2*64 + 64];
            half8 Bk2n0 = wck[18*2*64],  Bk2n1 = wck[18*2*64 + 64];
#pragma unroll
            for (int s = 0; s < 2; ++s) {
                int ii = ib + s + dr, jj = jj0 + dc;
                bool valid = ((unsigned)ii < HH) && ((unsigned)jj < WW);
                int tr = ii - (ib - 2), tc = jj - (j0b - 2);
                int loff = (tr * TCOLS + tc) * 8;
                union { half8 s8; uint4 u; } A0, A1, A2;
                A0.u = *(const uint4*)&xsm[lg * (TPX * 8) + loff];
                A1.u = *(const uint4*)&xsm[(4 + lg) * (TPX * 8) + loff];
                if (!valid) {
                    A0.u.x = 0; A0.u.y = 0; A0.u.z = 0; A0.u.w = 0;
                    A1.u.x = 0; A1.u.y = 0; A1.u.z = 0; A1.u.w = 0;
                }
                unsigned am = (valid && lg == 0)
                            ? (unsigned)(unsigned short)f2h(msm[tr * TCOLS + tc]) : 0u;
                A2.u.x = am; A2.u.y = 0; A2.u.z = 0; A2.u.w = 0;
                if (s == 0) {
                    ca00 = __builtin_amdgcn_mfma_f32_16x16x32_f16(A0.s8, Bk0n0, ca00, 0, 0, 0);
                    ca01 = __builtin_amdgcn_mfma_f32_16x16x32_f16(A0.s8, Bk0n1, ca01, 0, 0, 0);
                    ca00 = __builtin_amdgcn_mfma_f32_16x16x32_f16(A1.s8, Bk1n0, ca00, 0, 0, 0);
                    ca01 = __builtin_amdgcn_mfma_f32_16x16x32_f16(A1.s8, Bk1n1, ca01, 0, 0, 0);
                    ca00 = __builtin_amdgcn_mfma_f32_16x16x32_f16(A2.s8, Bk2n0, ca00, 0, 0, 0);
                    ca01 = __builtin_amdgcn_mfma_f32_16x16x32_f16(A2.s8, Bk2n1, ca01, 0, 0, 0);
                } else {
                    ca10 = __builtin_amdgcn_mfma_f32_16x16x32_f16(A0.s8, Bk0n0, ca10, 0, 0, 0);
                    ca11 = __builtin_amdgcn_mfma_f32_16x16x32_f16(A0.s8, Bk0n1, ca11, 0, 0, 0);
                    ca10 = __builtin_amdgcn_mfma_f32_16x16x32_f16(A1.s8, Bk1n0, ca10, 0, 0, 0);
                    ca11 = __builtin_amdgcn_mfma_f32_16x16x32_f16(A1.s8, Bk1n1, ca11, 0, 0, 0);
                    ca10 = __builtin_amdgcn_mfma_f32_16x16x32_f16(A2.s8, Bk2n0, ca10, 0, 0, 0);
                    ca11 = __builtin_amdgcn_mfma_f32_16x16x32_f16(A2.s8, Bk2n1, ca11, 0, 0, 0);
                }
            }
        }
        int oc = lane & 15, pr0 = lg * 4;
#pragma unroll
        for (int s = 0; s < 2; ++s) {
            const f32x4& c0 = s ? ca10 : ca00;
            const f32x4& c1 = s ? ca11 : ca01;
#pragma unroll
            for (int rr = 0; rr < 4; ++rr) {
                int px = s * 64 + w * 16 + pr0 + rr;
                offsm[px * 32 + oc] = f2h(c0[rr] + offset_b[oc]);
                int oc2 = 16 + oc;
                if (oc2 < 18) {
                    offsm[px * 32 + oc2] = f2h(c1[rr] + offset_b[oc2]);
                } else if (oc2 < 27) {
                    float z = c1[rr] + mask_b[oc2 - 18];
                    offsm[px * 32 + oc2] = f2h(1.f / (1.f + __expf(-z)));
                }
            }
        }
    }
    __syncthreads();

    // ---- Phase 2: deformable conv, 2 pixel-sets per wave, B reused across sets ----
    float ov0[28], ov1[28];
#pragma unroll
    for (int s = 0; s < 2; ++s) {
        int px = s * 64 + w * 16 + r;
        float* ov = s ? ov1 : ov0;
        const U4* op = (const U4*)&offsm[px * 32];
#pragma unroll
        for (int q4 = 0; q4 < 4; ++q4) {
            U4 t = op[q4];
#pragma unroll
            for (int e = 0; e < 4; ++e) {
                int base = q4 * 8 + e * 2;
                if (base < 28) {
                    HU hu; hu.u = t.a[e];
                    ov[base] = (float)hu.h[0];
                    ov[base + 1] = (float)hu.h[1];
                }
            }
        }
    }

    f32x4 ac00 = {0,0,0,0}, ac01 = {0,0,0,0}, ac02 = {0,0,0,0}, ac03 = {0,0,0,0};
    f32x4 ac10 = {0,0,0,0}, ac11 = {0,0,0,0}, ac12 = {0,0,0,0}, ac13 = {0,0,0,0};
    float um0 = 0.f, um1 = 0.f;

#pragma unroll
    for (int k = 0; k < KK; ++k) {
        // B frags for this tap (shared by both sets)
        const half8* w0 = wd + ((0 * 9 + k) * 4) * 64 + lane;
        const half8* w1 = wd + ((1 * 9 + k) * 4) * 64 + lane;
        half8 B00 = w0[0], B01 = w0[64], B02 = w0[128], B03 = w0[192];
        half8 B10 = w1[0], B11 = w1[64], B12 = w1[128], B13 = w1[192];

#pragma unroll
        for (int s = 0; s < 2; ++s) {
            const float* ov = s ? ov1 : ov0;
            int i = ib + s, j = jj0;
            float dy = ov[2*k], dx = ov[2*k+1], m = ov[18+k];
            float py  = dy + (float)(k / 3 + i - 1);
            float pxx = dx + (float)(k % 3 + j - 1);
            float fy = floorf(py), fx = floorf(pxx);
            float wy = py - fy, wx = pxx - fx;
            int y0 = (int)fy, x0 = (int)fx;
            int y1 = y0 + 1, x1 = x0 + 1;
            bool vy0 = (unsigned)y0 < HH, vy1 = (unsigned)y1 < HH;
            bool vx0 = (unsigned)x0 < WW, vx1 = (unsigned)x1 < WW;
            int yc0 = min(max(y0, 0), HH - 1), yc1 = min(max(y1, 0), HH - 1);
            int xc0 = min(max(x0, 0), WW - 1), xc1 = min(max(x1, 0), WW - 1);
            float r00 = (vy0 && vx0) ? (1.f - wy) * (1.f - wx) : 0.f;
            float r01 = (vy0 && vx1) ? (1.f - wy) * wx : 0.f;
            float r10 = (vy1 && vx0) ? wy * (1.f - wx) : 0.f;
            float r11 = (vy1 && vx1) ? wy * wx : 0.f;

            int tr0 = yc0 - (ib - 2), tr1 = yc1 - (ib - 2);
            int tc0 = xc0 - (j0b - 2), tc1 = xc1 - (j0b - 2);
            bool in00 = ((unsigned)tr0 < (unsigned)TROWS) & ((unsigned)tc0 < (unsigned)TCOLS);
            bool in01 = ((unsigned)tr0 < (unsigned)TROWS) & ((unsigned)tc1 < (unsigned)TCOLS);
            bool in10 = ((unsigned)tr1 < (unsigned)TROWS) & ((unsigned)tc0 < (unsigned)TCOLS);
            bool in11 = ((unsigned)tr1 < (unsigned)TROWS) & ((unsigned)tc1 < (unsigned)TCOLS);
            int trc0 = min(max(tr0, 0), TROWS - 1), trc1 = min(max(tr1, 0), TROWS - 1);
            int tcc0 = min(max(tc0, 0), TCOLS - 1), tcc1 = min(max(tc1, 0), TCOLS - 1);
            int l00 = trc0 * TCOLS + tcc0, l01 = trc0 * TCOLS + tcc1;
            int l10 = trc1 * TCOLS + tcc0, l11 = trc1 * TCOLS + tcc1;

            U4 g00[2], g01[2], g10[2], g11[2];
#pragma unroll
            for (int ks = 0; ks < 2; ++ks) {
                const short* xs = xsm + (size_t)(ks * 4 + lg) * (TPX * 8);
                g00[ks].v = *(const uint4*)(xs + l00 * 8);
                g01[ks].v = *(const uint4*)(xs + l01 * 8);
                g10[ks].v = *(const uint4*)(xs + l10 * 8);
                g11[ks].v = *(const uint4*)(xs + l11 * 8);
            }
            float m00 = msm[l00], m01 = msm[l01], m10 = msm[l10], m11 = msm[l11];

            if (!__all(in00 & in01 & in10 & in11)) {
                int p00 = yc0 * WW + xc0, p01 = yc0 * WW + xc1;
                int p10 = yc1 * WW + xc0, p11 = yc1 * WW + xc1;
                if (!in00) {
                    g00[0].v = *(const uint4*)(xq + (size_t)p00 * 8);
                    g00[1].v = *(const uint4*)(xq + 4 * PS + (size_t)p00 * 8);
                    m00 = mb[p00];
                }
                if (!in01) {
                    g01[0].v = *(const uint4*)(xq + (size_t)p01 * 8);
                    g01[1].v = *(const uint4*)(xq + 4 * PS + (size_t)p01 * 8);
                    m01 = mb[p01];
                }
                if (!in10) {
                    g10[0].v = *(const uint4*)(xq + (size_t)p10 * 8);
                    g10[1].v = *(const uint4*)(xq + 4 * PS + (size_t)p10 * 8);
                    m10 = mb[p10];
                }
                if (!in11) {
                    g11[0].v = *(const uint4*)(xq + (size_t)p11 * 8);
                    g11[1].v = *(const uint4*)(xq + 4 * PS + (size_t)p11 * 8);
                    m11 = mb[p11];
                }
            }

            float umv = r00 * m00 + r01 * m01 + r10 * m10 + r11 * m11;
            if (s == 0) um0 += umv; else um1 += umv;

            float w00 = r00 * m, w01 = r01 * m, w10 = r10 * m, w11 = r11 * m;
            h2 w00h = { (_Float16)w00, (_Float16)w00 };
            h2 w01h = { (_Float16)w01, (_Float16)w01 };
            h2 w10h = { (_Float16)w10, (_Float16)w10 };
            h2 w11h = { (_Float16)w11, (_Float16)w11 };

#pragma unroll
            for (int ks = 0; ks < 2; ++ks) {
                union { half8 s8; unsigned u[4]; } A;
#pragma unroll
                for (int q = 0; q < 4; ++q) {
                    HU a00, a01, a10, a11, res;
                    a00.u = g00[ks].a[q]; a01.u = g01[ks].a[q];
                    a10.u = g10[ks].a[q]; a11.u = g11[ks].a[q];
                    h2 acc = a00.h * w00h;
                    acc = a01.h * w01h + acc;
                    acc = a10.h * w10h + acc;
                    acc = a11.h * w11h + acc;
                    res.h = acc;
                    A.u[q] = res.u;
                }
                if (s == 0) {
                    if (ks == 0) {
                        ac00 = __builtin_amdgcn_mfma_f32_16x16x32_f16(A.s8, B00, ac00, 0, 0, 0);
                        ac01 = __builtin_amdgcn_mfma_f32_16x16x32_f16(A.s8, B01, ac01, 0, 0, 0);
                        ac02 = __builtin_amdgcn_mfma_f32_16x16x32_f16(A.s8, B02, ac02, 0, 0, 0);
                        ac03 = __builtin_amdgcn_mfma_f32_16x16x32_f16(A.s8, B03, ac03, 0, 0, 0);
                    } else {
                        ac00 = __builtin_amdgcn_mfma_f32_16x16x32_f16(A.s8, B10, ac00, 0, 0, 0);
                        ac01 = __builtin_amdgcn_mfma_f32_16x16x32_f16(A.s8, B11, ac01, 0, 0, 0);
                        ac02 = __builtin_amdgcn_mfma_f32_16x16x32_f16(A.s8, B12, ac02, 0, 0, 0);
                        ac03 = __builtin_amdgcn_mfma_f32_16x16x32_f16(A.s8, B13, ac03, 0, 0, 0);
                    }
                } else {
                    if (ks == 0) {
                        ac10 = __builtin_amdgcn_mfma_f32_16x16x32_f16(A.s8, B00, ac10, 0, 0, 0);
                        ac11 = __builtin_amdgcn_mfma_f32_16x16x32_f16(A.s8, B01, ac11, 0, 0, 0);
                        ac12 = __builtin_amdgcn_mfma_f32_16x16x32_f16(A.s8, B02, ac12, 0, 0, 0);
                        ac13 = __builtin_amdgcn_mfma_f32_16x16x32_f16(A.s8, B03, ac13, 0, 0, 0);
                    } else {
                        ac10 = __builtin_amdgcn_mfma_f32_16x16x32_f16(A.s8, B10, ac10, 0, 0, 0);
                        ac11 = __builtin_amdgcn_mfma_f32_16x16x32_f16(A.s8, B11, ac11, 0, 0, 0);
                        ac12 = __builtin_amdgcn_mfma_f32_16x16x32_f16(A.s8, B12, ac12, 0, 0, 0);
                        ac13 = __builtin_amdgcn_mfma_f32_16x16x32_f16(A.s8, B13, ac13, 0, 0, 0);
                    }
                }
            }
        }
    }

    um0 = fminf(fmaxf(64.f * um0, 0.f), 1.f);
    um1 = fminf(fmaxf(64.f * um1, 0.f), 1.f);
    if (lane < 16) {
        upd[(size_t)b * HWSZ + (ib + 0) * WW + jw + lane] = um0;
        upd[(size_t)b * HWSZ + (ib + 1) * WW + jw + lane] = um1;
    }

    int oc = lane & 15;
    int pr0 = lg * 4;
    float u0[4], u1[4];
#pragma unroll
    for (int rr = 0; rr < 4; ++rr) {
        u0[rr] = __shfl(um0, pr0 + rr, 64);
        u1[rr] = __shfl(um1, pr0 + rr, 64);
    }

    // ---- Phase 3: transpose epilogue through LDS (reuse xsm), coalesced NCHW stores ----
    __syncthreads();
    float* outsm = (float*)xsm;      // [128 px][stride 65] = 33,280 B
#define STORE_NT(ACC, NT, S, U)                                               \
    {                                                                         \
        float bo = bias[(NT) * 16 + oc];                                      \
        _Pragma("unroll")                                                     \
        for (int rr = 0; rr < 4; ++rr) {                                      \
            int px = (S) * 64 + w * 16 + pr0 + rr;                            \
            outsm[px * 65 + (NT) * 16 + oc] = (ACC[rr] + bo) * U[rr];         \
        }                                                                     \
    }
    STORE_NT(ac00, 0, 0, u0) STORE_NT(ac01, 1, 0, u0)
    STORE_NT(ac02, 2, 0, u0) STORE_NT(ac03, 3, 0, u0)
    STORE_NT(ac10, 0, 1, u1) STORE_NT(ac11, 1, 1, u1)
    STORE_NT(ac12, 2, 1, u1) STORE_NT(ac13, 3, 1, u1)
#undef STORE_NT
    __syncthreads();
    {
        int ch = threadIdx.x >> 2, q = threadIdx.x & 3;   // q: 32-px chunk
        int row = q >> 1, colh = (q & 1) * 32;
        float* dst = out + ((size_t)(b * 64 + ch)) * HWSZ + (ib + row) * WW + j0b + colh;
#pragma unroll
        for (int gq = 0; gq < 8; ++gq) {
            int px = q * 32 + gq * 4;
            float4 v = { outsm[(px + 0) * 65 + ch], outsm[(px + 1) * 65 + ch],
                         outsm[(px + 2) * 65 + ch], outsm[(px + 3) * 65 + ch] };
            *(float4*)(dst + gq * 4) = v;
        }
    }
}

extern "C" void kernel_launch(void* const* d_in, const int* in_sizes, int n_in,
                              void* d_out, int out_size, void* d_ws, size_t ws_size,
                              hipStream_t stream) {
    const float* input    = (const float*)d_in[0];
    const float* mask_in  = (const float*)d_in[1];
    const float* weight   = (const float*)d_in[2];
    const float* bias     = (const float*)d_in[3];
    const float* offset_w = (const float*)d_in[4];
    const float* offset_b = (const float*)d_in[5];
    const float* mask_w   = (const float*)d_in[6];
    const float* mask_b   = (const float*)d_in[7];

    float* out = (float*)d_out;
    float* upd = out + (size_t)NB * 64 * HWSZ;

    short* wd2 = (short*)d_ws;                 // 36,864 f16
    short* wc2 = wd2 + 36864;                  // 27,648 f16
    short* xt2 = wc2 + 27648;                  // 4*12*16384*8 f16 = 12.6 MB

    hipLaunchKernelGGL(prep_kernel, dim3(1168), dim3(256), 0, stream,
                       input, mask_in, weight, offset_w, mask_w, xt2, wd2, wc2);
    hipLaunchKernelGGL(fused_conv_deform, dim3(512), dim3(256), 0, stream,
                       xt2, mask_in, (const half8*)wc2, (const half8*)wd2,
                       offset_b, mask_b, bias, out, upd);
}